// Round 2
// baseline (163.441 us; speedup 1.0000x reference)
//
#include <hip/hip_runtime.h>

// CorpusSupportSets, round 2: two-kernel split.
//  K1 (idx scan): stream mask[BS,K], scatter one-hot index -> ws. No reductions.
//  K2 (main): per-wave sample compute with a SINGLE 6-value shuffle-reduce round.
//
// Inputs (fp32): mask[BS,K], z[BS,DIM], SUPPORT_SETS[K,2*DIM], ALPHAS[K,2],
// LOGGAMMA[K,2].  Output (fp32): [BS,DIM].

constexpr int K   = 1000;
constexpr int DIM = 768;
constexpr int VPR = K / 4;   // float4 vectors per mask row = 250

__global__ __launch_bounds__(256) void css_idx_kernel(
    const float4* __restrict__ mask4, int* __restrict__ idx, int nvec)
{
    int i = blockIdx.x * blockDim.x + threadIdx.x;
    const int stride = gridDim.x * blockDim.x;
    for (; i < nvec; i += stride) {
        float4 v = mask4[i];
        if (v.x != 0.f || v.y != 0.f || v.z != 0.f || v.w != 0.f) {
            int b = i / VPR;                 // compiler magic-mul
            int j = (i - b * VPR) * 4;
            int c = (v.x != 0.f) ? 0 : (v.y != 0.f) ? 1 : (v.z != 0.f) ? 2 : 3;
            idx[b] = j + c;
        }
    }
}

__global__ __launch_bounds__(256) void css_main_kernel(
    const int*   __restrict__ idx,
    const float* __restrict__ z,
    const float* __restrict__ ss,
    const float* __restrict__ alphas,
    const float* __restrict__ loggamma,
    float* __restrict__ out,
    int bs)
{
    const int gid  = blockIdx.x * blockDim.x + threadIdx.x;
    const int b    = gid >> 6;          // one wave per sample
    const int lane = threadIdx.x & 63;
    if (b >= bs) return;

    // index (same address across the wave -> single broadcast load); clamp
    // defends against an all-zero row leaving ws poisoned (0xAAAAAAAA < 0).
    int k = idx[b];
    k = (k < 0) ? 0 : (k >= K ? K - 1 : k);

    // dipole params — tiny, L2-resident, broadcast loads; issue early.
    const float a0 = alphas[2 * k];
    const float a1 = alphas[2 * k + 1];
    const float lg0 = loggamma[2 * k];
    const float lg1 = loggamma[2 * k + 1];

    const float4* zrow = (const float4*)(z + (size_t)b * DIM);
    const float4* srow = (const float4*)(ss + (size_t)k * (2 * DIM));

    float4 z4[3], d0[3], d1[3];
    // 6 independent partials, reduced in ONE butterfly round:
    float sqn0 = 0.f, sqn1 = 0.f, zd0 = 0.f, zd1 = 0.f, d01 = 0.f, zsq = 0.f;
    #pragma unroll
    for (int i = 0; i < 3; ++i) {
        z4[i] = zrow[lane + i * 64];
        float4 s0 = srow[lane + i * 64];
        float4 s1 = srow[192 + lane + i * 64];
        d0[i].x = z4[i].x - s0.x;  d0[i].y = z4[i].y - s0.y;
        d0[i].z = z4[i].z - s0.z;  d0[i].w = z4[i].w - s0.w;
        d1[i].x = z4[i].x - s1.x;  d1[i].y = z4[i].y - s1.y;
        d1[i].z = z4[i].z - s1.z;  d1[i].w = z4[i].w - s1.w;
        sqn0 += d0[i].x*d0[i].x + d0[i].y*d0[i].y + d0[i].z*d0[i].z + d0[i].w*d0[i].w;
        sqn1 += d1[i].x*d1[i].x + d1[i].y*d1[i].y + d1[i].z*d1[i].z + d1[i].w*d1[i].w;
        zd0  += z4[i].x*d0[i].x + z4[i].y*d0[i].y + z4[i].z*d0[i].z + z4[i].w*d0[i].w;
        zd1  += z4[i].x*d1[i].x + z4[i].y*d1[i].y + z4[i].z*d1[i].z + z4[i].w*d1[i].w;
        d01  += d0[i].x*d1[i].x + d0[i].y*d1[i].y + d0[i].z*d1[i].z + d0[i].w*d1[i].w;
        zsq  += z4[i].x*z4[i].x + z4[i].y*z4[i].y + z4[i].z*z4[i].z + z4[i].w*z4[i].w;
    }
    #pragma unroll
    for (int off = 1; off < 64; off <<= 1) {
        sqn0 += __shfl_xor(sqn0, off, 64);
        sqn1 += __shfl_xor(sqn1, off, 64);
        zd0  += __shfl_xor(zd0,  off, 64);
        zd1  += __shfl_xor(zd1,  off, 64);
        d01  += __shfl_xor(d01,  off, 64);
        zsq  += __shfl_xor(zsq,  off, 64);
    }

    // scalar algebra (all lanes redundantly):
    const float g0 = expf(lg0);
    const float g1 = expf(lg1);
    const float c0 = -2.f * a0 * g0 * expf(-g0 * sqn0);
    const float c1 = -2.f * a1 * g1 * expf(-g1 * sqn1);
    const float dot    = c0 * zd0 + c1 * zd1;                       // z . grad
    const float gradsq = c0*c0*sqn0 + 2.f*c0*c1*d01 + c1*c1*sqn1;   // ||grad||^2
    const float nsq    = gradsq - 2.f*dot*dot + dot*dot*zsq;        // ||proj||^2 (exact)
    const float inv    = 1.f / sqrtf(nsq);

    float4* orow = (float4*)(out + (size_t)b * DIM);
    #pragma unroll
    for (int i = 0; i < 3; ++i) {
        float4 r;
        r.x = (c0*d0[i].x + c1*d1[i].x - dot*z4[i].x) * inv;
        r.y = (c0*d0[i].y + c1*d1[i].y - dot*z4[i].y) * inv;
        r.z = (c0*d0[i].z + c1*d1[i].z - dot*z4[i].z) * inv;
        r.w = (c0*d0[i].w + c1*d1[i].w - dot*z4[i].w) * inv;
        orow[lane + i * 64] = r;
    }
}

extern "C" void kernel_launch(void* const* d_in, const int* in_sizes, int n_in,
                              void* d_out, int out_size, void* d_ws, size_t ws_size,
                              hipStream_t stream) {
    const float* mask     = (const float*)d_in[0];
    const float* z        = (const float*)d_in[1];
    const float* ss       = (const float*)d_in[2];
    const float* alphas   = (const float*)d_in[3];
    const float* loggamma = (const float*)d_in[4];
    float* out = (float*)d_out;
    int*   idx = (int*)d_ws;                     // bs * 4 bytes of scratch

    const int bs   = in_sizes[1] / DIM;          // 16384
    const int nvec = bs * VPR;                   // mask float4 count

    // K1: ~4 float4s per thread, grid-stride
    const int k1_blocks = (nvec + 256 * 4 - 1) / (256 * 4);
    css_idx_kernel<<<k1_blocks, 256, 0, stream>>>((const float4*)mask, idx, nvec);

    // K2: one wave per sample, 4 waves per block
    const int k2_blocks = (bs + 3) / 4;
    css_main_kernel<<<k2_blocks, 256, 0, stream>>>(idx, z, ss, alphas, loggamma, out, bs);
}

// Round 4
// 155.047 us; speedup vs baseline: 1.0541x; 1.0541x over previous
//
#include <hip/hip_runtime.h>

// CorpusSupportSets, round 3b (fix: nontemporal builtins need native vector
// types, not HIP_vector_type — use clang ext_vector_type(4) float).
//  K1: wave-per-row one-hot scan with early exit (expected ~62.5% of mask read),
//      nontemporal loads, single idx store per row.
//  K2: per-wave sample compute, single 6-value shuffle-reduce round,
//      nontemporal output stores.

constexpr int K   = 1000;
constexpr int DIM = 768;
constexpr int VPR = K / 4;   // float4 vectors per mask row = 250

typedef float f4 __attribute__((ext_vector_type(4)));  // native vec4

__global__ __launch_bounds__(256) void css_idx_kernel(
    const f4* __restrict__ mask4, int* __restrict__ idx, int bs)
{
    const int b    = (blockIdx.x * blockDim.x + threadIdx.x) >> 6;
    const int lane = threadIdx.x & 63;
    if (b >= bs) return;

    const f4* mrow = mask4 + (size_t)b * VPR;
    int found = -1;
    #pragma unroll 1
    for (int i = 0; i < 4; ++i) {
        const int e = i * 64 + lane;
        if (e < VPR) {
            f4 v = __builtin_nontemporal_load(mrow + e);
            if (v.x != 0.f) found = e * 4 + 0;
            if (v.y != 0.f) found = e * 4 + 1;
            if (v.z != 0.f) found = e * 4 + 2;
            if (v.w != 0.f) found = e * 4 + 3;
        }
        // wave-uniform early exit: one-hot guarantees at most one lane hits
        if (__ballot(found >= 0)) break;
    }
    #pragma unroll
    for (int off = 1; off < 64; off <<= 1)
        found = max(found, __shfl_xor(found, off, 64));
    if (lane == 0) idx[b] = found;
}

__global__ __launch_bounds__(256) void css_main_kernel(
    const int*   __restrict__ idx,
    const float* __restrict__ z,
    const float* __restrict__ ss,
    const float* __restrict__ alphas,
    const float* __restrict__ loggamma,
    float* __restrict__ out,
    int bs)
{
    const int gid  = blockIdx.x * blockDim.x + threadIdx.x;
    const int b    = gid >> 6;          // one wave per sample
    const int lane = threadIdx.x & 63;
    if (b >= bs) return;

    // Independent z loads first — hide the k-dependent chain behind them.
    const f4* zrow = (const f4*)(z + (size_t)b * DIM);
    f4 z4[3];
    #pragma unroll
    for (int i = 0; i < 3; ++i) z4[i] = zrow[lane + i * 64];

    // One broadcast load for the wave; clamp defends vs all-zero row / poison.
    int k = idx[b];
    k = (k < 0) ? 0 : (k >= K ? K - 1 : k);

    const float a0  = alphas[2 * k];
    const float a1  = alphas[2 * k + 1];
    const float lg0 = loggamma[2 * k];
    const float lg1 = loggamma[2 * k + 1];

    const f4* srow = (const f4*)(ss + (size_t)k * (2 * DIM));

    f4 d0[3], d1[3];
    // 6 independent partials, reduced in ONE butterfly round:
    float sqn0 = 0.f, sqn1 = 0.f, zd0 = 0.f, zd1 = 0.f, d01 = 0.f, zsq = 0.f;
    #pragma unroll
    for (int i = 0; i < 3; ++i) {
        f4 s0 = srow[lane + i * 64];
        f4 s1 = srow[192 + lane + i * 64];
        d0[i] = z4[i] - s0;
        d1[i] = z4[i] - s1;
        sqn0 += d0[i].x*d0[i].x + d0[i].y*d0[i].y + d0[i].z*d0[i].z + d0[i].w*d0[i].w;
        sqn1 += d1[i].x*d1[i].x + d1[i].y*d1[i].y + d1[i].z*d1[i].z + d1[i].w*d1[i].w;
        zd0  += z4[i].x*d0[i].x + z4[i].y*d0[i].y + z4[i].z*d0[i].z + z4[i].w*d0[i].w;
        zd1  += z4[i].x*d1[i].x + z4[i].y*d1[i].y + z4[i].z*d1[i].z + z4[i].w*d1[i].w;
        d01  += d0[i].x*d1[i].x + d0[i].y*d1[i].y + d0[i].z*d1[i].z + d0[i].w*d1[i].w;
        zsq  += z4[i].x*z4[i].x + z4[i].y*z4[i].y + z4[i].z*z4[i].z + z4[i].w*z4[i].w;
    }
    #pragma unroll
    for (int off = 1; off < 64; off <<= 1) {
        sqn0 += __shfl_xor(sqn0, off, 64);
        sqn1 += __shfl_xor(sqn1, off, 64);
        zd0  += __shfl_xor(zd0,  off, 64);
        zd1  += __shfl_xor(zd1,  off, 64);
        d01  += __shfl_xor(d01,  off, 64);
        zsq  += __shfl_xor(zsq,  off, 64);
    }

    const float g0 = expf(lg0);
    const float g1 = expf(lg1);
    const float c0 = -2.f * a0 * g0 * expf(-g0 * sqn0);
    const float c1 = -2.f * a1 * g1 * expf(-g1 * sqn1);
    const float dot    = c0 * zd0 + c1 * zd1;                       // z . grad
    const float gradsq = c0*c0*sqn0 + 2.f*c0*c1*d01 + c1*c1*sqn1;   // ||grad||^2
    const float nsq    = gradsq - 2.f*dot*dot + dot*dot*zsq;        // ||proj||^2
    const float inv    = 1.f / sqrtf(nsq);

    f4* orow = (f4*)(out + (size_t)b * DIM);
    #pragma unroll
    for (int i = 0; i < 3; ++i) {
        f4 r = (c0 * d0[i] + c1 * d1[i] - dot * z4[i]) * inv;
        __builtin_nontemporal_store(r, orow + lane + i * 64);
    }
}

extern "C" void kernel_launch(void* const* d_in, const int* in_sizes, int n_in,
                              void* d_out, int out_size, void* d_ws, size_t ws_size,
                              hipStream_t stream) {
    const float* mask     = (const float*)d_in[0];
    const float* z        = (const float*)d_in[1];
    const float* ss       = (const float*)d_in[2];
    const float* alphas   = (const float*)d_in[3];
    const float* loggamma = (const float*)d_in[4];
    float* out = (float*)d_out;
    int*   idx = (int*)d_ws;                     // bs * 4 bytes of scratch

    const int bs = in_sizes[1] / DIM;            // 16384

    // K1: one wave per row, 4 rows per block
    const int k1_blocks = (bs + 3) / 4;
    css_idx_kernel<<<k1_blocks, 256, 0, stream>>>((const f4*)mask, idx, bs);

    // K2: one wave per sample, 4 samples per block
    const int k2_blocks = (bs + 3) / 4;
    css_main_kernel<<<k2_blocks, 256, 0, stream>>>(idx, z, ss, alphas, loggamma, out, bs);
}